// Round 1
// baseline (7879.814 us; speedup 1.0000x reference)
//
#include <hip/hip_runtime.h>

// ---------------------------------------------------------------------------
// LSTM feedback model: 288 warmup steps + 287 AR steps + readout.
//   B=1024, F=32, U=512. AR feedback folded: z = h@(R + Wd@W) + (b + bd@W).
//   Preds = 2 extra MFMA columns per block, computed in the NEXT step's GEMM.
// Decomposition: 16 row-groups x 64 rows, 16-way N-split -> 256 blocks (1/CU),
//   512 threads = 8 waves (wave w: m = w&3 -> M-tile, n2 = w>>2 -> unit half).
//   Weight chunk pre-swizzled to B-fragment order, LDS-resident all steps.
//   h double-buffered in ws (bf16); c in registers (C-fragment layout).
//   Per-step 16-block barrier: monotonic device-scope atomic counter.
// ---------------------------------------------------------------------------

#define NRG_     16
#define NSPLIT_  16
#define MB_      64
#define TW_      288
#define NSTEPS_  576
#define UU_      512
#define OUTT_    288
#define OUTF_    32
#define GW_CHUNK_  69632    // 17 ktiles * 8 slots * 64 lanes * 8 elems
#define GAR_CHUNK_ 73728    // 16 ktiles * 9 slots * 64 lanes * 8 elems

typedef __bf16  bf16x8 __attribute__((ext_vector_type(8)));
typedef float   f32x4  __attribute__((ext_vector_type(4)));
typedef float   f32x8  __attribute__((ext_vector_type(8)));

#define MFMA16(A, B, C) __builtin_amdgcn_mfma_f32_16x16x32_bf16((A), (B), (C), 0, 0, 0)

__device__ __forceinline__ unsigned short f2bf(float v) {
  union { float f; unsigned u; } x; x.f = v;
  unsigned r = x.u + 0x7fffu + ((x.u >> 16) & 1u);   // RNE
  return (unsigned short)(r >> 16);
}
__device__ __forceinline__ float sigm(float x) {
  return __builtin_amdgcn_rcpf(1.0f + __expf(-x));
}
__device__ __forceinline__ float tanh_(float x) {
  return 2.0f * __builtin_amdgcn_rcpf(1.0f + __expf(-2.0f * x)) - 1.0f;
}

// ---------------------------------------------------------------------------
// Prep: build swizzled bf16 weight chunks + folded AR weights/bias.
//  Gw  chunk j: [kt 0..16][slot 0..7][lane][8]   slot = n2*4 + gate
//               k<512 -> R[k][c], k>=512 -> W[k-512][c], c = gate*512 + unit
//  Gar chunk j: [kt 0..15][slot 0..8][lane][8]   slot 8 = pred cols (Wd)
//               gates: R_ar = R + Wd@W ; pred: col p<2 -> Wd[k][2j+p]
// ---------------------------------------------------------------------------
__global__ void prep_kernel(const float* __restrict__ W, const float* __restrict__ R,
                            const float* __restrict__ b, const float* __restrict__ Wd,
                            const float* __restrict__ bd,
                            unsigned short* __restrict__ Gw,
                            unsigned short* __restrict__ Gar,
                            float* __restrict__ b_ar) {
  const long NGW  = (long)NSPLIT_ * GW_CHUNK_;
  const long NGAR = (long)NSPLIT_ * GAR_CHUNK_;
  long idx = (long)blockIdx.x * blockDim.x + threadIdx.x;
  if (idx < NGW) {
    int t = (int)idx;
    int jj = t & 7, l = (t >> 3) & 63, s = (t >> 9) & 7;
    int rest = t >> 12;
    int kt = rest % 17, j = rest / 17;
    int k = kt * 32 + ((l >> 4) << 3) + jj;
    int u = j * 32 + ((s >> 2) << 4) + (l & 15);
    int c = ((s & 3) << 9) + u;
    float v = (k < 512) ? R[(long)k * 2048 + c] : W[(long)(k - 512) * 2048 + c];
    Gw[t] = f2bf(v);
  } else if (idx < NGW + NGAR) {
    int t = (int)(idx - NGW);
    int jj = t & 7, l = (t >> 3) & 63;
    int rest = t >> 9;
    int s = rest % 9; rest /= 9;
    int kt = rest & 15, j = rest >> 4;
    int k = kt * 32 + ((l >> 4) << 3) + jj;
    float v;
    if (s < 8) {
      int u = j * 32 + ((s >> 2) << 4) + (l & 15);
      int c = ((s & 3) << 9) + u;
      float acc = R[(long)k * 2048 + c];
      for (int f = 0; f < 32; ++f) acc += Wd[k * 32 + f] * W[(long)f * 2048 + c];
      v = acc;
    } else {
      int p = l & 15;
      v = (p < 2) ? Wd[k * 32 + 2 * j + p] : 0.0f;
    }
    Gar[t] = f2bf(v);
  } else if (idx < NGW + NGAR + 2048) {
    int c = (int)(idx - NGW - NGAR);
    float acc = b[c];
    for (int f = 0; f < 32; ++f) acc += bd[f] * W[(long)f * 2048 + c];
    b_ar[c] = acc;
  }
}

// ---------------------------------------------------------------------------
__global__ __launch_bounds__(512, 2) void lstm_main(
    const float* __restrict__ xin,
    const float* __restrict__ bvec,
    const float* __restrict__ bdv,
    const float* __restrict__ b_ar,
    const unsigned short* __restrict__ Gw,
    const unsigned short* __restrict__ Gar,
    unsigned short* __restrict__ h0,
    unsigned short* __restrict__ h1,
    int* __restrict__ cnt,
    float* __restrict__ out)
{
  __shared__ uint4 smem4[GAR_CHUNK_ / 8];         // 147456 B LDS (1 block/CU)
  char* smem = (char*)smem4;

  const int bid = blockIdx.x;
  const int rg  = bid & 15;       // row-group (XCD-local-ish: rg%8 == bid%8)
  const int j   = bid >> 4;       // N-split id
  const int tid = threadIdx.x;
  const int l   = tid & 63;
  const int w   = tid >> 6;
  const int m   = w & 3;          // M-tile (16 rows)
  const int n2  = w >> 2;         // unit half; waves s,s+4 on one SIMD balance AR pred tile

  // stage warm weight chunk
  {
    const uint4* src = (const uint4*)(Gw + (size_t)j * GW_CHUNK_);
    for (int i = tid; i < GW_CHUNK_ / 8; i += 512) smem4[i] = src[i];
  }

  const int arow = rg * MB_ + m * 16 + (l & 15);        // A-frag row (batch)
  const int ahi  = (l >> 4) << 3;                       // A-frag k sub-offset
  const int ucol = j * 32 + (n2 << 4) + (l & 15);       // owned unit (C col)
  const int crow = rg * MB_ + m * 16 + ((l >> 4) << 2); // C row base
  const int pcol = l & 15;

  const float bw0 = bvec[ucol],        bw1 = bvec[512 + ucol],
              bw2 = bvec[1024 + ucol], bw3 = bvec[1536 + ucol];
  const float ba0 = b_ar[ucol],        ba1 = b_ar[512 + ucol],
              ba2 = b_ar[1024 + ucol], ba3 = b_ar[1536 + ucol];
  const float bp  = (pcol < 2) ? bdv[2 * j + pcol] : 0.0f;

  float c_st[4] = {0.0f, 0.0f, 0.0f, 0.0f};

  // x prefetch for st=0 (x never depends on the barrier)
  f32x8 xv = *(const f32x8*)(xin + (size_t)arow * (TW_ * 32) + ahi);

  __syncthreads();

  const char* lbase = smem + l * 16;
  const int sboff = (n2 << 2) * 1024;

  for (int st = 0; st < NSTEPS_; ++st) {
    const bool warm = (st < TW_);
    const unsigned short* hs = (st & 1) ? h1 : h0;
    unsigned short*       hd = (st & 1) ? h0 : h1;

    if (st == TW_) {                       // swap LDS to folded AR weights
      __syncthreads();
      const uint4* src = (const uint4*)(Gar + (size_t)j * GAR_CHUNK_);
      for (int i = tid; i < GAR_CHUNK_ / 8; i += 512) smem4[i] = src[i];
      __syncthreads();
    }

    // A fragments: h (bf16, [row][unit] ld=512) -> 16B loads per ktile
    bf16x8 a[17];
    {
      const unsigned short* hp = hs + (size_t)arow * UU_ + ahi;
      #pragma unroll
      for (int kt = 0; kt < 16; ++kt)
        a[kt] = *(const bf16x8*)(hp + kt * 32);
    }

    f32x4 ai = {0,0,0,0}, af = {0,0,0,0}, ag = {0,0,0,0}, ao = {0,0,0,0}, ap = {0,0,0,0};

    if (warm) {
      bf16x8 ax;
      #pragma unroll
      for (int e = 0; e < 8; ++e) ax[e] = (__bf16)xv[e];
      a[16] = ax;                           // x_t as K-rows 512..543
      #pragma unroll
      for (int kt = 0; kt < 17; ++kt) {
        const char* kb = lbase + kt * 8192 + sboff;
        ai = MFMA16(a[kt], *(const bf16x8*)(kb        ), ai);
        af = MFMA16(a[kt], *(const bf16x8*)(kb + 1024), af);
        ag = MFMA16(a[kt], *(const bf16x8*)(kb + 2048), ag);
        ao = MFMA16(a[kt], *(const bf16x8*)(kb + 3072), ao);
      }
    } else if (st < NSTEPS_ - 1) {
      #pragma unroll
      for (int kt = 0; kt < 16; ++kt) {
        const char* kb = lbase + kt * 9216;
        const char* gb = kb + sboff;
        ai = MFMA16(a[kt], *(const bf16x8*)(gb        ), ai);
        af = MFMA16(a[kt], *(const bf16x8*)(gb + 1024), af);
        ag = MFMA16(a[kt], *(const bf16x8*)(gb + 2048), ag);
        ao = MFMA16(a[kt], *(const bf16x8*)(gb + 3072), ao);
        if (n2) ap = MFMA16(a[kt], *(const bf16x8*)(kb + 8192), ap);
      }
    } else {                                // final step: pred tile only
      if (n2) {
        #pragma unroll
        for (int kt = 0; kt < 16; ++kt)
          ap = MFMA16(a[kt], *(const bf16x8*)(lbase + kt * 9216 + 8192), ap);
      }
    }

    if (st < NSTEPS_ - 1) {
      const float bi = warm ? bw0 : ba0;
      const float bff = warm ? bw1 : ba1;
      const float bgg = warm ? bw2 : ba2;
      const float boo = warm ? bw3 : ba3;
      unsigned short* hw = hd + (size_t)crow * UU_ + ucol;
      #pragma unroll
      for (int r = 0; r < 4; ++r) {
        const float ig = sigm(ai[r] + bi);
        const float fg = sigm(af[r] + bff);
        const float gg = tanh_(ag[r] + bgg);
        const float og = sigm(ao[r] + boo);
        const float cc = fg * c_st[r] + ig * gg;
        c_st[r] = cc;
        hw[(size_t)r * UU_] = f2bf(og * tanh_(cc));
      }
    }

    // pred from previous h (lands one step later); st>=288 -> out step st-288
    if (!warm && n2 && pcol < 2) {
      float* op = out + (size_t)crow * (OUTT_ * OUTF_)
                      + (size_t)(st - TW_) * OUTF_ + (2 * j + pcol);
      #pragma unroll
      for (int r = 0; r < 4; ++r)
        op[(size_t)r * (OUTT_ * OUTF_)] = ap[r] + bp;
    }

    // prefetch next x under the barrier
    if (st + 1 < TW_) {
      xv = *(const f32x8*)(xin + ((size_t)arow * TW_ + (st + 1)) * 32 + ahi);
    }

    // row-group barrier (16 blocks), monotonic counter
    if (st < NSTEPS_ - 1) {
      __syncthreads();                      // drains stores (vmcnt0 before s_barrier)
      if (tid == 0) {
        __hip_atomic_fetch_add(&cnt[rg * 64], 1, __ATOMIC_RELEASE, __HIP_MEMORY_SCOPE_AGENT);
        const int target = (st + 1) * NSPLIT_;
        while (__hip_atomic_load(&cnt[rg * 64], __ATOMIC_RELAXED, __HIP_MEMORY_SCOPE_AGENT) < target) {
          __builtin_amdgcn_s_sleep(1);
        }
        __threadfence();                    // acquire: invalidate L1/L2 before h reads
      }
      __syncthreads();
    }
  }
}

// ---------------------------------------------------------------------------
extern "C" void kernel_launch(void* const* d_in, const int* in_sizes, int n_in,
                              void* d_out, int out_size, void* d_ws, size_t ws_size,
                              hipStream_t stream) {
  (void)in_sizes; (void)n_in; (void)out_size; (void)ws_size;
  const float* x  = (const float*)d_in[0];
  const float* W  = (const float*)d_in[1];
  const float* R  = (const float*)d_in[2];
  const float* b  = (const float*)d_in[3];
  const float* Wd = (const float*)d_in[4];
  const float* bd = (const float*)d_in[5];
  float* out = (float*)d_out;

  // ws carve (needs ~6.4 MiB)
  char* ws = (char*)d_ws;
  unsigned short* Gw   = (unsigned short*)(ws + 0);        // 2,228,224 B
  unsigned short* Gar  = (unsigned short*)(ws + 2228224);  // 2,359,296 B
  float*          b_ar = (float*)(ws + 4587520);           // 8,192 B
  unsigned short* h0   = (unsigned short*)(ws + 4595712);  // 1 MiB
  unsigned short* h1   = (unsigned short*)(ws + 5644288);  // 1 MiB
  int*            cnt  = (int*)(ws + 6692864);             // 16 counters @256B

  hipMemsetAsync(h0, 0, 1048576, stream);
  hipMemsetAsync(cnt, 0, 16 * 64 * sizeof(int), stream);

  const long total = 16L * GW_CHUNK_ + 16L * GAR_CHUNK_ + 2048L;
  const int nb = (int)((total + 255) / 256);
  prep_kernel<<<nb, 256, 0, stream>>>(W, R, b, Wd, bd, Gw, Gar, b_ar);

  void* args[] = {(void*)&x, (void*)&b, (void*)&bd, (void*)&b_ar,
                  (void*)&Gw, (void*)&Gar, (void*)&h0, (void*)&h1,
                  (void*)&cnt, (void*)&out};
  hipLaunchCooperativeKernel((void*)lstm_main, dim3(256), dim3(512), args, 0, stream);
}

// Round 3
// 5582.222 us; speedup vs baseline: 1.4116x; 1.4116x over previous
//
#include <hip/hip_runtime.h>

// ---------------------------------------------------------------------------
// LSTM feedback model: 288 warmup steps + 287 AR steps + readout.
//   B=1024, F=32, U=512. AR feedback folded: z = h@(R + Wd@W) + (b + bd@W).
//   Preds = 2 extra MFMA columns per block, computed in the NEXT step's GEMM.
// Decomposition: 16 row-groups x 64 rows, 16-way N-split -> 256 blocks (1/CU),
//   512 threads = 8 waves (wave w: m = w&3 -> M-tile, n2 = w>>2 -> unit half).
//   Weight chunk pre-swizzled to B-fragment order, LDS-resident all steps.
//   h double-buffered in ws (bf16); c in registers (C-fragment layout).
// Sync: NO cache-maintenance fences. h exchanged via sc0sc1 (relaxed AGENT
//   atomic) stores/loads that bypass L1/L2 to the coherence point; per-
//   producer flag words + 16-lane parallel poll form the step barrier.
// R3 fix: LDS transpose staging (ushort writes / ull reads) is TBAA-unsafe
//   without ordering -> sandwich a __syncthreads between write and read.
// ---------------------------------------------------------------------------

#define NRG_     16
#define NSPLIT_  16
#define MB_      64
#define TW_      288
#define NSTEPS_  576
#define UU_      512
#define OUTT_    288
#define OUTF_    32
#define GW_CHUNK_  69632    // 17 ktiles * 8 slots * 64 lanes * 8 elems
#define GAR_CHUNK_ 73728    // 16 ktiles * 9 slots * 64 lanes * 8 elems

typedef __bf16  bf16x8 __attribute__((ext_vector_type(8)));
typedef float   f32x4  __attribute__((ext_vector_type(4)));
typedef float   f32x8  __attribute__((ext_vector_type(8)));

#define MFMA16(A, B, C) __builtin_amdgcn_mfma_f32_16x16x32_bf16((A), (B), (C), 0, 0, 0)
#define AGENT_ __HIP_MEMORY_SCOPE_AGENT

__device__ __forceinline__ unsigned short f2bf(float v) {
  union { float f; unsigned u; } x; x.f = v;
  unsigned r = x.u + 0x7fffu + ((x.u >> 16) & 1u);   // RNE
  return (unsigned short)(r >> 16);
}
__device__ __forceinline__ float sigm(float x) {
  return __builtin_amdgcn_rcpf(1.0f + __expf(-x));
}
__device__ __forceinline__ float tanh_(float x) {
  return 2.0f * __builtin_amdgcn_rcpf(1.0f + __expf(-2.0f * x)) - 1.0f;
}

// ---------------------------------------------------------------------------
// Prep: build swizzled bf16 weight chunks + folded AR weights/bias (unchanged).
// ---------------------------------------------------------------------------
__global__ void prep_kernel(const float* __restrict__ W, const float* __restrict__ R,
                            const float* __restrict__ b, const float* __restrict__ Wd,
                            const float* __restrict__ bd,
                            unsigned short* __restrict__ Gw,
                            unsigned short* __restrict__ Gar,
                            float* __restrict__ b_ar) {
  const long NGW  = (long)NSPLIT_ * GW_CHUNK_;
  const long NGAR = (long)NSPLIT_ * GAR_CHUNK_;
  long idx = (long)blockIdx.x * blockDim.x + threadIdx.x;
  if (idx < NGW) {
    int t = (int)idx;
    int jj = t & 7, l = (t >> 3) & 63, s = (t >> 9) & 7;
    int rest = t >> 12;
    int kt = rest % 17, j = rest / 17;
    int k = kt * 32 + ((l >> 4) << 3) + jj;
    int u = j * 32 + ((s >> 2) << 4) + (l & 15);
    int c = ((s & 3) << 9) + u;
    float v = (k < 512) ? R[(long)k * 2048 + c] : W[(long)(k - 512) * 2048 + c];
    Gw[t] = f2bf(v);
  } else if (idx < NGW + NGAR) {
    int t = (int)(idx - NGW);
    int jj = t & 7, l = (t >> 3) & 63;
    int rest = t >> 9;
    int s = rest % 9; rest /= 9;
    int kt = rest & 15, j = rest >> 4;
    int k = kt * 32 + ((l >> 4) << 3) + jj;
    float v;
    if (s < 8) {
      int u = j * 32 + ((s >> 2) << 4) + (l & 15);
      int c = ((s & 3) << 9) + u;
      float acc = R[(long)k * 2048 + c];
      for (int f = 0; f < 32; ++f) acc += Wd[k * 32 + f] * W[(long)f * 2048 + c];
      v = acc;
    } else {
      int p = l & 15;
      v = (p < 2) ? Wd[k * 32 + 2 * j + p] : 0.0f;
    }
    Gar[t] = f2bf(v);
  } else if (idx < NGW + NGAR + 2048) {
    int c = (int)(idx - NGW - NGAR);
    float acc = b[c];
    for (int f = 0; f < 32; ++f) acc += bd[f] * W[(long)f * 2048 + c];
    b_ar[c] = acc;
  }
}

// ---------------------------------------------------------------------------
__global__ __launch_bounds__(512, 2) void lstm_main(
    const float* __restrict__ xin,
    const float* __restrict__ bvec,
    const float* __restrict__ bdv,
    const float* __restrict__ b_ar,
    const unsigned short* __restrict__ Gw,
    const unsigned short* __restrict__ Gar,
    unsigned long long* __restrict__ h0,   // bf16 h, viewed as 8B words
    unsigned long long* __restrict__ h1,
    int* __restrict__ flags,               // [rg][16] per-producer step flags
    float* __restrict__ out)
{
  __shared__ uint4 smem4[GAR_CHUNK_ / 8];           // 147456 B weights
  __shared__ unsigned long long hstg[512];          // 4 KB: 8 waves x 64 ull
  char* smem = (char*)smem4;

  const int bid = blockIdx.x;
  const int rg  = bid & 15;       // all 16 blocks of a rg share bid%8 (XCD)
  const int j   = bid >> 4;       // N-split id
  const int tid = threadIdx.x;
  const int l   = tid & 63;
  const int w   = tid >> 6;
  const int m   = w & 3;          // M-tile (16 rows)
  const int n2  = w >> 2;         // unit half

  // stage warm weight chunk
  {
    const uint4* src = (const uint4*)(Gw + (size_t)j * GW_CHUNK_);
    for (int i = tid; i < GW_CHUNK_ / 8; i += 512) smem4[i] = src[i];
  }

  const int arow = rg * MB_ + m * 16 + (l & 15);        // A-frag row (batch)
  const int ahi  = (l >> 4) << 3;                       // A-frag k sub-offset
  const int aull = arow * 128 + (ahi >> 2);             // ull index into h row
  const int ucol = j * 32 + (n2 << 4) + (l & 15);       // owned unit (C col)
  const int crow = rg * MB_ + m * 16 + ((l >> 4) << 2); // C row base
  const int pcol = l & 15;

  // h writeback geometry (after LDS transpose): one 8B chunk per lane
  const int wrow = rg * MB_ + m * 16 + (l >> 2);        // global h row
  const int wull = wrow * 128 + j * 8 + n2 * 4 + (l & 3);
  unsigned short* hb = (unsigned short*)hstg + (w << 8);

  const float bw0 = bvec[ucol],        bw1 = bvec[512 + ucol],
              bw2 = bvec[1024 + ucol], bw3 = bvec[1536 + ucol];
  const float ba0 = b_ar[ucol],        ba1 = b_ar[512 + ucol],
              ba2 = b_ar[1024 + ucol], ba3 = b_ar[1536 + ucol];
  const float bp  = (pcol < 2) ? bdv[2 * j + pcol] : 0.0f;

  float c_st[4] = {0.0f, 0.0f, 0.0f, 0.0f};

  // x prefetch for st=0 (x never depends on the barrier)
  f32x8 xv = *(const f32x8*)(xin + (size_t)arow * (TW_ * 32) + ahi);

  __syncthreads();

  const char* lbase = smem + l * 16;
  const int sboff = (n2 << 2) * 1024;

  for (int st = 0; st < NSTEPS_; ++st) {
    const bool warm = (st < TW_);
    const bool produce = (st < NSTEPS_ - 1);
    unsigned long long* hs = (st & 1) ? h1 : h0;
    unsigned long long* hd = (st & 1) ? h0 : h1;

    if (st == TW_) {                       // swap LDS to folded AR weights
      __syncthreads();
      const uint4* src = (const uint4*)(Gar + (size_t)j * GAR_CHUNK_);
      for (int i = tid; i < GAR_CHUNK_ / 8; i += 512) smem4[i] = src[i];
      __syncthreads();
    }

    // A fragments: coherent (sc0 sc1) 8B loads straight from L3 — no staleness
    bf16x8 a[17];
    #pragma unroll
    for (int kt = 0; kt < 16; ++kt) {
      union { unsigned long long q[2]; bf16x8 v; } u;
      unsigned long long* p = hs + aull + kt * 8;
      u.q[0] = __hip_atomic_load(p,     __ATOMIC_RELAXED, AGENT_);
      u.q[1] = __hip_atomic_load(p + 1, __ATOMIC_RELAXED, AGENT_);
      a[kt] = u.v;
    }

    f32x4 ai = {0,0,0,0}, af = {0,0,0,0}, ag = {0,0,0,0}, ao = {0,0,0,0}, ap = {0,0,0,0};

    if (warm) {
      bf16x8 ax;
      #pragma unroll
      for (int e = 0; e < 8; ++e) ax[e] = (__bf16)xv[e];
      a[16] = ax;                           // x_t as K-rows 512..543
      #pragma unroll
      for (int kt = 0; kt < 17; ++kt) {
        const char* kb = lbase + kt * 8192 + sboff;
        ai = MFMA16(a[kt], *(const bf16x8*)(kb        ), ai);
        af = MFMA16(a[kt], *(const bf16x8*)(kb + 1024), af);
        ag = MFMA16(a[kt], *(const bf16x8*)(kb + 2048), ag);
        ao = MFMA16(a[kt], *(const bf16x8*)(kb + 3072), ao);
      }
    } else if (produce) {
      #pragma unroll
      for (int kt = 0; kt < 16; ++kt) {
        const char* kb = lbase + kt * 9216;
        const char* gb = kb + sboff;
        ai = MFMA16(a[kt], *(const bf16x8*)(gb        ), ai);
        af = MFMA16(a[kt], *(const bf16x8*)(gb + 1024), af);
        ag = MFMA16(a[kt], *(const bf16x8*)(gb + 2048), ag);
        ao = MFMA16(a[kt], *(const bf16x8*)(gb + 3072), ao);
        if (n2) ap = MFMA16(a[kt], *(const bf16x8*)(kb + 8192), ap);
      }
    } else {                                // final step: pred tile only
      if (n2) {
        #pragma unroll
        for (int kt = 0; kt < 16; ++kt)
          ap = MFMA16(a[kt], *(const bf16x8*)(lbase + kt * 9216 + 8192), ap);
      }
    }

    if (produce) {
      const float bi  = warm ? bw0 : ba0;
      const float bff = warm ? bw1 : ba1;
      const float bgg = warm ? bw2 : ba2;
      const float boo = warm ? bw3 : ba3;
      #pragma unroll
      for (int r = 0; r < 4; ++r) {
        const float ig = sigm(ai[r] + bi);
        const float fg = sigm(af[r] + bff);
        const float gg = tanh_(ag[r] + bgg);
        const float og = sigm(ao[r] + boo);
        const float cc = fg * c_st[r] + ig * gg;
        c_st[r] = cc;
        // LDS micro-transpose: [16 rows][16 units] per wave
        hb[(((l >> 4) << 2) + r) * 16 + (l & 15)] = f2bf(og * tanh_(cc));
      }
    }

    // R3: barrier between transpose write (ushort) and read (ull).
    // Full compiler memory fence (kills TBAA reorder) + lgkm drain.
    __syncthreads();

    if (produce) {
      // read back one contiguous 8B chunk, coherent store (bypasses L1/L2)
      unsigned long long v = hstg[(w << 6) + l];
      __hip_atomic_store(hd + wull, v, __ATOMIC_RELAXED, AGENT_);
    }

    // pred from previous h (lands one step later); st>=288 -> out step st-288
    if (!warm && n2 && pcol < 2) {
      float* op = out + (size_t)crow * (OUTT_ * OUTF_)
                      + (size_t)(st - TW_) * OUTF_ + (2 * j + pcol);
      #pragma unroll
      for (int r = 0; r < 4; ++r)
        op[(size_t)r * (OUTT_ * OUTF_)] = ap[r] + bp;
    }

    // prefetch next x
    if (st + 1 < TW_) {
      xv = *(const f32x8*)(xin + ((size_t)arow * TW_ + (st + 1)) * 32 + ahi);
    }

    // step barrier: per-producer flags, no fences, no cache maintenance.
    // __syncthreads drains vmcnt -> our sc0sc1 h stores are at the coherence
    // point before the flag store; consumers' sc0sc1 loads can't go stale.
    if (produce) {
      __syncthreads();
      if (tid < 64) {                       // wave 0 handles the protocol
        if (tid == 0)
          __hip_atomic_store(&flags[rg * 16 + j], st + 1, __ATOMIC_RELAXED, AGENT_);
        const int need = st + 1;
        bool ok;
        do {
          int f = (tid < 16)
                    ? __hip_atomic_load(&flags[rg * 16 + tid], __ATOMIC_RELAXED, AGENT_)
                    : need;
          ok = (f >= need);
        } while (!__all(ok));
      }
      __syncthreads();
    }
  }
}

// ---------------------------------------------------------------------------
extern "C" void kernel_launch(void* const* d_in, const int* in_sizes, int n_in,
                              void* d_out, int out_size, void* d_ws, size_t ws_size,
                              hipStream_t stream) {
  (void)in_sizes; (void)n_in; (void)out_size; (void)ws_size;
  const float* x  = (const float*)d_in[0];
  const float* W  = (const float*)d_in[1];
  const float* R  = (const float*)d_in[2];
  const float* b  = (const float*)d_in[3];
  const float* Wd = (const float*)d_in[4];
  const float* bd = (const float*)d_in[5];
  float* out = (float*)d_out;

  // ws carve (needs ~6.4 MiB)
  char* ws = (char*)d_ws;
  unsigned short*     Gw    = (unsigned short*)(ws + 0);        // 2,228,224 B
  unsigned short*     Gar   = (unsigned short*)(ws + 2228224);  // 2,359,296 B
  float*              b_ar  = (float*)(ws + 4587520);           // 8,192 B
  unsigned long long* h0    = (unsigned long long*)(ws + 4595712);  // 1 MiB
  unsigned long long* h1    = (unsigned long long*)(ws + 5644288);  // 1 MiB
  int*                flags = (int*)(ws + 6692864);             // 16*16 ints

  hipMemsetAsync(h0, 0, 1048576, stream);
  hipMemsetAsync(flags, 0, NRG_ * NSPLIT_ * sizeof(int), stream);

  const long total = 16L * GW_CHUNK_ + 16L * GAR_CHUNK_ + 2048L;
  const int nb = (int)((total + 255) / 256);
  prep_kernel<<<nb, 256, 0, stream>>>(W, R, b, Wd, bd, Gw, Gar, b_ar);

  void* args[] = {(void*)&x, (void*)&b, (void*)&bd, (void*)&b_ar,
                  (void*)&Gw, (void*)&Gar, (void*)&h0, (void*)&h1,
                  (void*)&flags, (void*)&out};
  hipLaunchCooperativeKernel((void*)lstm_main, dim3(256), dim3(512), args, 0, stream);
}

// Round 4
// 2861.710 us; speedup vs baseline: 2.7535x; 1.9507x over previous
//
#include <hip/hip_runtime.h>

// ---------------------------------------------------------------------------
// LSTM feedback model: 288 warmup steps + 287 AR steps + readout.
//   B=1024, F=32, U=512. AR feedback folded: z = h@(R + Wd@W) + (b + bd@W).
//   Preds = 2 extra MFMA columns per block, computed in the NEXT step's GEMM.
// Decomposition: 16 row-groups x 64 rows, 16-way N-split -> 256 blocks (1/CU),
//   512 threads = 8 waves (wave w: m = w&3 -> M-tile, n2 = w>>2 -> unit half).
//   Weight chunk pre-swizzled to B-fragment order, LDS-resident all steps.
//   h double-buffered in ws (bf16); c in registers (C-fragment layout).
// Sync: sc0sc1 (relaxed AGENT atomic) h stores/loads straight to the
//   coherence point; per-producer flag words + 16-lane poll = step barrier.
// R4: h exchanged in MFMA A-FRAGMENT LAYOUT -> every consumer load reads
//   512 B fully contiguous (was 8B @ 1KB stride = 2x line overfetch).
//   Chunk (rg, m, kt) = 1 KB: half0[l*8] = units kt*32+(l>>4)*8+{0..3} of
//   row rg*64+m*16+(l&15); half1[l*8] = +{4..7}.
// ---------------------------------------------------------------------------

#define NRG_     16
#define NSPLIT_  16
#define MB_      64
#define TW_      288
#define NSTEPS_  576
#define UU_      512
#define OUTT_    288
#define OUTF_    32
#define GW_CHUNK_  69632    // 17 ktiles * 8 slots * 64 lanes * 8 elems
#define GAR_CHUNK_ 73728    // 16 ktiles * 9 slots * 64 lanes * 8 elems

typedef __bf16  bf16x8 __attribute__((ext_vector_type(8)));
typedef float   f32x4  __attribute__((ext_vector_type(4)));
typedef float   f32x8  __attribute__((ext_vector_type(8)));

#define MFMA16(A, B, C) __builtin_amdgcn_mfma_f32_16x16x32_bf16((A), (B), (C), 0, 0, 0)
#define AGENT_ __HIP_MEMORY_SCOPE_AGENT

__device__ __forceinline__ unsigned short f2bf(float v) {
  union { float f; unsigned u; } x; x.f = v;
  unsigned r = x.u + 0x7fffu + ((x.u >> 16) & 1u);   // RNE
  return (unsigned short)(r >> 16);
}
__device__ __forceinline__ float sigm(float x) {
  return __builtin_amdgcn_rcpf(1.0f + __expf(-x));
}
__device__ __forceinline__ float tanh_(float x) {
  return 2.0f * __builtin_amdgcn_rcpf(1.0f + __expf(-2.0f * x)) - 1.0f;
}

// ---------------------------------------------------------------------------
// Prep: build swizzled bf16 weight chunks + folded AR weights/bias (unchanged).
// ---------------------------------------------------------------------------
__global__ void prep_kernel(const float* __restrict__ W, const float* __restrict__ R,
                            const float* __restrict__ b, const float* __restrict__ Wd,
                            const float* __restrict__ bd,
                            unsigned short* __restrict__ Gw,
                            unsigned short* __restrict__ Gar,
                            float* __restrict__ b_ar) {
  const long NGW  = (long)NSPLIT_ * GW_CHUNK_;
  const long NGAR = (long)NSPLIT_ * GAR_CHUNK_;
  long idx = (long)blockIdx.x * blockDim.x + threadIdx.x;
  if (idx < NGW) {
    int t = (int)idx;
    int jj = t & 7, l = (t >> 3) & 63, s = (t >> 9) & 7;
    int rest = t >> 12;
    int kt = rest % 17, j = rest / 17;
    int k = kt * 32 + ((l >> 4) << 3) + jj;
    int u = j * 32 + ((s >> 2) << 4) + (l & 15);
    int c = ((s & 3) << 9) + u;
    float v = (k < 512) ? R[(long)k * 2048 + c] : W[(long)(k - 512) * 2048 + c];
    Gw[t] = f2bf(v);
  } else if (idx < NGW + NGAR) {
    int t = (int)(idx - NGW);
    int jj = t & 7, l = (t >> 3) & 63;
    int rest = t >> 9;
    int s = rest % 9; rest /= 9;
    int kt = rest & 15, j = rest >> 4;
    int k = kt * 32 + ((l >> 4) << 3) + jj;
    float v;
    if (s < 8) {
      int u = j * 32 + ((s >> 2) << 4) + (l & 15);
      int c = ((s & 3) << 9) + u;
      float acc = R[(long)k * 2048 + c];
      for (int f = 0; f < 32; ++f) acc += Wd[k * 32 + f] * W[(long)f * 2048 + c];
      v = acc;
    } else {
      int p = l & 15;
      v = (p < 2) ? Wd[k * 32 + 2 * j + p] : 0.0f;
    }
    Gar[t] = f2bf(v);
  } else if (idx < NGW + NGAR + 2048) {
    int c = (int)(idx - NGW - NGAR);
    float acc = b[c];
    for (int f = 0; f < 32; ++f) acc += bd[f] * W[(long)f * 2048 + c];
    b_ar[c] = acc;
  }
}

// ---------------------------------------------------------------------------
__global__ __launch_bounds__(512, 2) void lstm_main(
    const float* __restrict__ xin,
    const float* __restrict__ bvec,
    const float* __restrict__ bdv,
    const float* __restrict__ b_ar,
    const unsigned short* __restrict__ Gw,
    const unsigned short* __restrict__ Gar,
    unsigned long long* __restrict__ h0,   // frag-layout bf16 h, 8B words
    unsigned long long* __restrict__ h1,
    int* __restrict__ flags,               // [rg][16] per-producer step flags
    float* __restrict__ out)
{
  __shared__ uint4 smem4[GAR_CHUNK_ / 8];           // 147456 B weights
  __shared__ unsigned long long hstg[512];          // 4 KB: 8 waves x 64 ull
  char* smem = (char*)smem4;

  const int bid = blockIdx.x;
  const int rg  = bid & 15;
  const int j   = bid >> 4;       // N-split id
  const int tid = threadIdx.x;
  const int l   = tid & 63;
  const int w   = tid >> 6;
  const int m   = w & 3;          // M-tile (16 rows)
  const int n2  = w >> 2;         // unit half

  // stage warm weight chunk
  {
    const uint4* src = (const uint4*)(Gw + (size_t)j * GW_CHUNK_);
    for (int i = tid; i < GW_CHUNK_ / 8; i += 512) smem4[i] = src[i];
  }

  const int arow = rg * MB_ + m * 16 + (l & 15);        // A-frag row (batch)
  const int ahi  = (l >> 4) << 3;                       // A-frag k sub-offset
  // consumer: frag-layout chunk base (ull idx); + kt*128 (+64 for hi half)
  const int abase = rg * 8192 + m * 2048 + l;
  const int ucol = j * 32 + (n2 << 4) + (l & 15);       // owned unit (C col)
  const int crow = rg * MB_ + m * 16 + ((l >> 4) << 2); // C row base
  const int pcol = l & 15;

  // producer: frag-layout writeback, one 8B chunk per lane (contiguous runs)
  const int wull = rg * 8192 + (m * 16 + j) * 128
                 + (l >> 5) * 64 + n2 * 32 + (l & 31);
  const int ridx = (w << 6) + ((l & 15) << 2) + ((l & 16) >> 3) + (l >> 5);
  unsigned short* hb = (unsigned short*)hstg + (w << 8);

  const float bw0 = bvec[ucol],        bw1 = bvec[512 + ucol],
              bw2 = bvec[1024 + ucol], bw3 = bvec[1536 + ucol];
  const float ba0 = b_ar[ucol],        ba1 = b_ar[512 + ucol],
              ba2 = b_ar[1024 + ucol], ba3 = b_ar[1536 + ucol];
  const float bp  = (pcol < 2) ? bdv[2 * j + pcol] : 0.0f;

  float c_st[4] = {0.0f, 0.0f, 0.0f, 0.0f};

  // x prefetch for st=0 (x never depends on the barrier)
  f32x8 xv = *(const f32x8*)(xin + (size_t)arow * (TW_ * 32) + ahi);

  __syncthreads();

  const char* lbase = smem + l * 16;
  const int sboff = (n2 << 2) * 1024;

  for (int st = 0; st < NSTEPS_; ++st) {
    const bool warm = (st < TW_);
    const bool produce = (st < NSTEPS_ - 1);
    unsigned long long* hs = (st & 1) ? h1 : h0;
    unsigned long long* hd = (st & 1) ? h0 : h1;

    if (st == TW_) {                       // swap LDS to folded AR weights
      __syncthreads();
      const uint4* src = (const uint4*)(Gar + (size_t)j * GAR_CHUNK_);
      for (int i = tid; i < GAR_CHUNK_ / 8; i += 512) smem4[i] = src[i];
      __syncthreads();
    }

    // A fragments: coherent 8B loads; frag layout -> 512 B contiguous / instr
    bf16x8 a[17];
    #pragma unroll
    for (int kt = 0; kt < 16; ++kt) {
      union { unsigned long long q[2]; bf16x8 v; } u;
      u.q[0] = __hip_atomic_load(hs + abase + kt * 128,      __ATOMIC_RELAXED, AGENT_);
      u.q[1] = __hip_atomic_load(hs + abase + kt * 128 + 64, __ATOMIC_RELAXED, AGENT_);
      a[kt] = u.v;
    }

    f32x4 ai = {0,0,0,0}, af = {0,0,0,0}, ag = {0,0,0,0}, ao = {0,0,0,0}, ap = {0,0,0,0};

    if (warm) {
      bf16x8 ax;
      #pragma unroll
      for (int e = 0; e < 8; ++e) ax[e] = (__bf16)xv[e];
      a[16] = ax;                           // x_t as K-rows 512..543
      #pragma unroll
      for (int kt = 0; kt < 17; ++kt) {
        const char* kb = lbase + kt * 8192 + sboff;
        ai = MFMA16(a[kt], *(const bf16x8*)(kb        ), ai);
        af = MFMA16(a[kt], *(const bf16x8*)(kb + 1024), af);
        ag = MFMA16(a[kt], *(const bf16x8*)(kb + 2048), ag);
        ao = MFMA16(a[kt], *(const bf16x8*)(kb + 3072), ao);
      }
    } else if (produce) {
      #pragma unroll
      for (int kt = 0; kt < 16; ++kt) {
        const char* kb = lbase + kt * 9216;
        const char* gb = kb + sboff;
        ai = MFMA16(a[kt], *(const bf16x8*)(gb        ), ai);
        af = MFMA16(a[kt], *(const bf16x8*)(gb + 1024), af);
        ag = MFMA16(a[kt], *(const bf16x8*)(gb + 2048), ag);
        ao = MFMA16(a[kt], *(const bf16x8*)(gb + 3072), ao);
        if (n2) ap = MFMA16(a[kt], *(const bf16x8*)(kb + 8192), ap);
      }
    } else {                                // final step: pred tile only
      if (n2) {
        #pragma unroll
        for (int kt = 0; kt < 16; ++kt)
          ap = MFMA16(a[kt], *(const bf16x8*)(lbase + kt * 9216 + 8192), ap);
      }
    }

    if (produce) {
      const float bi  = warm ? bw0 : ba0;
      const float bff = warm ? bw1 : ba1;
      const float bgg = warm ? bw2 : ba2;
      const float boo = warm ? bw3 : ba3;
      #pragma unroll
      for (int r = 0; r < 4; ++r) {
        const float ig = sigm(ai[r] + bi);
        const float fg = sigm(af[r] + bff);
        const float gg = tanh_(ag[r] + bgg);
        const float og = sigm(ao[r] + boo);
        const float cc = fg * c_st[r] + ig * gg;
        c_st[r] = cc;
        // LDS micro-transpose: [16 rows][16 units] per wave
        hb[(((l >> 4) << 2) + r) * 16 + (l & 15)] = f2bf(og * tanh_(cc));
      }
    }

    // barrier between transpose write (ushort) and read (ull):
    // compiler memory fence (TBAA) + lgkm drain.
    __syncthreads();

    if (produce) {
      unsigned long long v = hstg[ridx];
      __hip_atomic_store(hd + wull, v, __ATOMIC_RELAXED, AGENT_);
    }

    // pred from previous h (lands one step later); st>=288 -> out step st-288
    if (!warm && n2 && pcol < 2) {
      float* op = out + (size_t)crow * (OUTT_ * OUTF_)
                      + (size_t)(st - TW_) * OUTF_ + (2 * j + pcol);
      #pragma unroll
      for (int r = 0; r < 4; ++r)
        op[(size_t)r * (OUTT_ * OUTF_)] = ap[r] + bp;
    }

    // prefetch next x
    if (st + 1 < TW_) {
      xv = *(const f32x8*)(xin + ((size_t)arow * TW_ + (st + 1)) * 32 + ahi);
    }

    // step barrier: per-producer flags, no cache maintenance.
    if (produce) {
      __syncthreads();                      // each wave drains vmcnt -> h at L3
      if (tid < 64) {
        if (tid == 0)
          __hip_atomic_store(&flags[rg * 16 + j], st + 1, __ATOMIC_RELAXED, AGENT_);
        const int need = st + 1;
        bool ok;
        do {
          int f = (tid < 16)
                    ? __hip_atomic_load(&flags[rg * 16 + tid], __ATOMIC_RELAXED, AGENT_)
                    : need;
          ok = (f >= need);
        } while (!__all(ok));
      }
      __syncthreads();
    }
  }
}

// ---------------------------------------------------------------------------
extern "C" void kernel_launch(void* const* d_in, const int* in_sizes, int n_in,
                              void* d_out, int out_size, void* d_ws, size_t ws_size,
                              hipStream_t stream) {
  (void)in_sizes; (void)n_in; (void)out_size; (void)ws_size;
  const float* x  = (const float*)d_in[0];
  const float* W  = (const float*)d_in[1];
  const float* R  = (const float*)d_in[2];
  const float* b  = (const float*)d_in[3];
  const float* Wd = (const float*)d_in[4];
  const float* bd = (const float*)d_in[5];
  float* out = (float*)d_out;

  // ws carve (needs ~6.4 MiB)
  char* ws = (char*)d_ws;
  unsigned short*     Gw    = (unsigned short*)(ws + 0);        // 2,228,224 B
  unsigned short*     Gar   = (unsigned short*)(ws + 2228224);  // 2,359,296 B
  float*              b_ar  = (float*)(ws + 4587520);           // 8,192 B
  unsigned long long* h0    = (unsigned long long*)(ws + 4595712);  // 1 MiB
  unsigned long long* h1    = (unsigned long long*)(ws + 5644288);  // 1 MiB
  int*                flags = (int*)(ws + 6692864);             // 16*16 ints

  hipMemsetAsync(h0, 0, 1048576, stream);
  hipMemsetAsync(flags, 0, NRG_ * NSPLIT_ * sizeof(int), stream);

  const long total = 16L * GW_CHUNK_ + 16L * GAR_CHUNK_ + 2048L;
  const int nb = (int)((total + 255) / 256);
  prep_kernel<<<nb, 256, 0, stream>>>(W, R, b, Wd, bd, Gw, Gar, b_ar);

  void* args[] = {(void*)&x, (void*)&b, (void*)&bd, (void*)&b_ar,
                  (void*)&Gw, (void*)&Gar, (void*)&h0, (void*)&h1,
                  (void*)&flags, (void*)&out};
  hipLaunchCooperativeKernel((void*)lstm_main, dim3(256), dim3(512), args, 0, stream);
}